// Round 1
// baseline (9857.874 us; speedup 1.0000x reference)
//
#include <hip/hip_runtime.h>
#include <math.h>

// LSTM_53171695124900: 2-layer LSTM, H=1024, I=64, O=2, T=4096.
// Persistent kernel, 256 WGs x 512 threads.
// Round-11 = round-10 with the PHASE REORDERED to minimize the h1
// recurrence critical cycle (the steady-state period is
// IC-round-trip + serial A-chain; everything else should hide in the
// IC flight shadow):
//   - A-part now computes ONLY W_hh1.h1 (16 dot2, register weights);
//     the 4 ds_read_b128 h1 fragments are KEPT IN REGISTERS (hv0..3).
//   - h1 is published immediately after S2 (no W_ih2 dots, no h2 poll
//     residual in front of it anymore).
//   - W_ih2 dots (from hv regs), h2 poll finish, h2 staging, and the
//     B-part all move into the publish shadow; one barrier added (S2b).
//   - h1 poll is depth-2 software-pipelined: loads stay 2-deep in
//     flight, so tag-arrival detection granularity ~halves.
// Everything else (f16 LDS weights, tagged 8B pairs, early h2 read,
// hist output, sync protocol/tags) is identical to r10.

#define HID 1024
#define DIN 64
#define TSTEPS 4096
#define NWG 256
#define TPB 512

typedef unsigned long long u64;
typedef unsigned int u32;
typedef _Float16 f16x2 __attribute__((ext_vector_type(2)));
typedef __fp16   g16x2 __attribute__((ext_vector_type(2)));

// ws layout in u64 (8B tagged pairs):
//   [0, 2048)                 : h1 pairs, 2 slots x 1024
//   [2048, 2048 + 4097*1024)  : h2 pairs; hist mode = row per phase,
//                               fallback mode = rows (phase & 1)
#define H2_OFF 2048
#define WS_NEED_U64 (2048ull + 4097ull * 1024ull)
#define WS_NEED_BYTES (WS_NEED_U64 * 8ull)
#define WS_ZERO_BYTES 32768   // h1 slots (16KB) + h2 rows 0..1 (16KB)

// dynamic LDS: 8*512 uint4 f16 weights (64KB) + 2 x 640-u32 h staging
#define WLDS_U4 (8 * 512)
#define H1S_OFF (WLDS_U4 * 16)            // bytes
#define H2S_OFF (H1S_OFF + 640 * 4)
#define DYN_LDS_BYTES (H2S_OFF + 640 * 4) // 70656 B

__device__ __forceinline__ float sigmoid_f(float v) {
    return 1.0f / (1.0f + __expf(-v));
}
__device__ __forceinline__ float tanh_f(float v) {
    return 2.0f / (1.0f + __expf(-2.0f * v)) - 1.0f;
}

// relaxed agent-scope 8B atomics: coherent at IC, no cache-maintenance insts
__device__ __forceinline__ void st_pair(u64* p, float h, u32 tag) {
    u64 pk = ((u64)tag << 32) | (u64)__float_as_uint(h);
    __hip_atomic_store(p, pk, __ATOMIC_RELAXED, __HIP_MEMORY_SCOPE_AGENT);
}
__device__ __forceinline__ u64 ld_pair(const u64* p) {
    return __hip_atomic_load(p, __ATOMIC_RELAXED, __HIP_MEMORY_SCOPE_AGENT);
}
#define PTAG(v) ((u32)((v) >> 32))
#define PVAL(v) (__uint_as_float((u32)(v)))

// same 4 bytes seen as u32 / __fp16x2 (cvt_pkrtz) / _Float16x2 (fdot2)
union U32H2 { u32 u; f16x2 h; g16x2 g; };

// pack two f32 -> half2 u32 (v_cvt_pkrtz_f16_f32, single inst)
__device__ __forceinline__ u32 pk2(float a, float b) {
    U32H2 t; t.g = __builtin_amdgcn_cvt_pkrtz(a, b); return t.u;
}

#if defined(__has_builtin)
#if __has_builtin(__builtin_amdgcn_fdot2)
#define HAS_FDOT2 1
#endif
#endif

// f32 += half2 . half2  (v_dot2_f32_f16 when available)
__device__ __forceinline__ float dot2f(u32 a, u32 b, float c) {
    U32H2 x, y; x.u = a; y.u = b;
#ifdef HAS_FDOT2
    return __builtin_amdgcn_fdot2(x.h, y.h, c, false);
#else
    float r = fmaf((float)x.h.x, (float)y.h.x, c);
    return fmaf((float)x.h.y, (float)y.h.y, r);
#endif
}

#define PIN_W1() asm volatile("" : "+v"(w1p0), "+v"(w1p1), "+v"(w1p2), \
    "+v"(w1p3), "+v"(w1p4), "+v"(w1p5), "+v"(w1p6), "+v"(w1p7), \
    "+v"(w1p8), "+v"(w1p9), "+v"(w1pA), "+v"(w1pB), \
    "+v"(w1pC), "+v"(w1pD), "+v"(w1pE), "+v"(w1pF))

// shadow W_ih2 step j (j=0..3): reuses hv regs, reads W2 from LDS
#define A2STEP(j, HV) do {                                          \
    uint4 w2 = wlds[(j)*512 + tid];                                 \
    e0 = dot2f(HV.x, w2.x, e0); e1 = dot2f(HV.y, w2.y, e1);         \
    e0 = dot2f(HV.z, w2.z, e0); e1 = dot2f(HV.w, w2.w, e1);         \
} while (0)

// B-step j (j=0..3): 8 h2 elems; W3 (LDS) -> accB
#define BSTEP(j) do {                                               \
    uint4 gv = *(const uint4*)(h2s + hbase + 4*(j));                \
    uint4 w3 = wlds[(4+(j))*512 + tid];                             \
    e0 = dot2f(gv.x, w3.x, e0); e1 = dot2f(gv.y, w3.y, e1);         \
    e0 = dot2f(gv.z, w3.z, e0); e1 = dot2f(gv.w, w3.w, e1);         \
} while (0)

__global__ void
__attribute__((amdgpu_flat_work_group_size(TPB, TPB), amdgpu_waves_per_eu(2, 2)))
lstm_persistent(
    const float* __restrict__ x,
    const float* __restrict__ Wih1, const float* __restrict__ Whh1,
    const float* __restrict__ bih1, const float* __restrict__ bhh1,
    const float* __restrict__ Wih2, const float* __restrict__ Whh2,
    const float* __restrict__ bih2, const float* __restrict__ bhh2,
    const float* __restrict__ Wout, const float* __restrict__ bout,
    float* __restrict__ out, u64* __restrict__ ws, int use_hist)
{
    const int wg   = blockIdx.x;          // 0..255
    const int tid  = threadIdx.x;         // 0..511
    const int wave = tid >> 6;            // 0..7
    const int lane = tid & 63;
    const int gate = tid >> 7;            // 0..3 (i,f,g,o)
    const int rsub = (tid >> 5) & 3;      // local unit 0..3
    const int c    = tid & 31;            // k-chunk 0..31
    const int row  = gate * HID + (wg << 2) + rsub;   // gate row in [0,4096)
    const int kbase = c << 5;

    u64* h1t = ws;
    u64* h2t = ws + H2_OFF;

    // ---- dynamic LDS carve ----
    extern __shared__ __align__(16) char smem[];
    uint4* wlds = (uint4*)smem;                  // 64KB f16 weights
    u32*   h1s  = (u32*)(smem + H1S_OFF);        // 640 u32 (stride-20 rows)
    u32*   h2s  = (u32*)(smem + H2S_OFF);        // 640 u32

    // ---- one-time: stage W_ih2/W_hh2 rows into LDS as packed f16 ----
    {
        const float4* q2 = (const float4*)(Wih2 + (size_t)row * HID + kbase);
        const float4* q3 = (const float4*)(Whh2 + (size_t)row * HID + kbase);
        #pragma unroll
        for (int j = 0; j < 4; ++j) {
            float4 qa = q2[2*j], qb = q2[2*j+1];
            wlds[j * 512 + tid] = make_uint4(pk2(qa.x, qa.y), pk2(qa.z, qa.w),
                                             pk2(qb.x, qb.y), pk2(qb.z, qb.w));
        }
        #pragma unroll
        for (int j = 0; j < 4; ++j) {
            float4 qa = q3[2*j], qb = q3[2*j+1];
            wlds[(4+j) * 512 + tid] = make_uint4(pk2(qa.x, qa.y), pk2(qa.z, qa.w),
                                                 pk2(qb.x, qb.y), pk2(qb.z, qb.w));
        }
    }

    // ---- W_hh1 row chunk: 16 packed-half2 u32 registers ----
    const float4* p1 = (const float4*)(Whh1 + (size_t)row * HID + kbase);
    float4 f0 = p1[0], f1 = p1[1], f2 = p1[2], f3 = p1[3];
    float4 f4 = p1[4], f5 = p1[5], f6 = p1[6], f7 = p1[7];
    u32 w1p0 = pk2(f0.x, f0.y), w1p1 = pk2(f0.z, f0.w);
    u32 w1p2 = pk2(f1.x, f1.y), w1p3 = pk2(f1.z, f1.w);
    u32 w1p4 = pk2(f2.x, f2.y), w1p5 = pk2(f2.z, f2.w);
    u32 w1p6 = pk2(f3.x, f3.y), w1p7 = pk2(f3.z, f3.w);
    u32 w1p8 = pk2(f4.x, f4.y), w1p9 = pk2(f4.z, f4.w);
    u32 w1pA = pk2(f5.x, f5.y), w1pB = pk2(f5.z, f5.w);
    u32 w1pC = pk2(f6.x, f6.y), w1pD = pk2(f6.z, f6.w);
    u32 w1pE = pk2(f7.x, f7.y), w1pF = pk2(f7.z, f7.w);
    PIN_W1();

    const float2 wx = *(const float2*)(Wih1 + (size_t)row * DIN + (c << 1));
    const float bsum1 = bih1[row] + bhh1[row];
    const float bsum2 = bih2[row] + bhh2[row];

    __shared__ float g1[4][4], g2[4][4];
    __shared__ float c1s[4], c2s[4];
    __shared__ float red0[8], red1[8];
    if (tid < 4) { c1s[tid] = 0.0f; c2s[tid] = 0.0f; }

    // h staging: chunk rows of 16 half2-u32 + 4 pad (stride 20 u32, 80B)
    const int sdst = 20 * (tid >> 4) + (tid & 15);
    const int hbase = 20 * c;

    __syncthreads();   // wlds staged, c-state zeroed

    for (int p = 0; p <= TSTEPS; ++p) {
        const u64* h1p = h1t + (size_t)(p & 1) * 1024 + (tid << 1);
        const int h2row_c = (p > 0) ? (use_hist ? (p - 1) : ((p - 1) & 1)) : 0;
        const u64* h2p = h2t + (size_t)h2row_c * 1024 + (tid << 1);
        const u32 want1 = (u32)p;
        const u32 want2 = (p >= 2) ? (u32)p : 0u;

        const int tx = (p < TSTEPS) ? p : 0;
        const float2 xv = *(const float2*)(x + (size_t)tx * DIN + (c << 1));

        // ---- blocking poll: h1(p), tag p; depth-2 pipelined so the
        //      tag-arrival detection granularity is ~half an IC latency ----
        u64 v1a, v1b;
        {
            u64 pa = ld_pair(h1p), pb = ld_pair(h1p + 1);
            int guard = 0;
            for (;;) {
                u64 na = ld_pair(h1p), nb = ld_pair(h1p + 1);
                if ((PTAG(pa) == want1) & (PTAG(pb) == want1)) {
                    v1a = pa; v1b = pb; break;
                }
                pa = na; pb = nb;
                if (++guard > (1 << 17)) { v1a = na; v1b = nb; break; }
            }
        }
        // early h2 read attempt (verified in the shadow region)
        u64 v2a = ld_pair(h2p), v2b = ld_pair(h2p + 1);

        PIN_W1();   // keepalive: W1 VGPR-resident every phase

        h1s[sdst] = pk2(PVAL(v1a), PVAL(v1b));
        __syncthreads();   // S1: h1s staged

        // ---- critical A1: accA = W_hh1 . h1 (+ x); h1 frags kept in regs ----
        uint4 hv0 = *(const uint4*)(h1s + hbase + 0);
        uint4 hv1 = *(const uint4*)(h1s + hbase + 4);
        uint4 hv2 = *(const uint4*)(h1s + hbase + 8);
        uint4 hv3 = *(const uint4*)(h1s + hbase + 12);
        float a0 = 0.f, a1 = 0.f;
        a0 = dot2f(hv0.x, w1p0, a0); a1 = dot2f(hv0.y, w1p1, a1);
        a0 = dot2f(hv0.z, w1p2, a0); a1 = dot2f(hv0.w, w1p3, a1);
        a0 = dot2f(hv1.x, w1p4, a0); a1 = dot2f(hv1.y, w1p5, a1);
        a0 = dot2f(hv1.z, w1p6, a0); a1 = dot2f(hv1.w, w1p7, a1);
        a0 = dot2f(hv2.x, w1p8, a0); a1 = dot2f(hv2.y, w1p9, a1);
        a0 = dot2f(hv2.z, w1pA, a0); a1 = dot2f(hv2.w, w1pB, a1);
        a0 = dot2f(hv3.x, w1pC, a0); a1 = dot2f(hv3.y, w1pD, a1);
        a0 = dot2f(hv3.z, w1pE, a0); a1 = dot2f(hv3.w, w1pF, a1);
        a0 = fmaf(wx.x, xv.x, a0);
        a1 = fmaf(wx.y, xv.y, a1);

        float accA = a0 + a1;
        accA += __shfl_xor(accA, 1);
        accA += __shfl_xor(accA, 2);
        accA += __shfl_xor(accA, 4);
        accA += __shfl_xor(accA, 8);
        accA += __shfl_xor(accA, 16);
        if (c == 0) {
            float vA = accA + bsum1;
            g1[gate][rsub] = (gate == 2) ? tanh_f(vA) : sigmoid_f(vA);
        }
        __syncthreads();   // S2: g1 ready

        // ---- EARLY h1 publication: nothing else in front of it now ----
        if (p < TSTEPS && tid < 4) {
            float iv = g1[0][tid], fv = g1[1][tid];
            float gv = g1[2][tid], ov = g1[3][tid];
            float cn = fv * c1s[tid] + iv * gv;
            c1s[tid] = cn;
            st_pair(h1t + (size_t)((p + 1) & 1) * 1024 + (wg << 2) + tid,
                    ov * tanh_f(cn), (u32)(p + 1));
        }

        // ---- shadow: accB partial = W_ih2 . h1 (hv regs x LDS W2) ----
        float e0 = 0.f, e1 = 0.f;
        A2STEP(0, hv0);
        A2STEP(1, hv1);
        A2STEP(2, hv2);
        A2STEP(3, hv3);

        // ---- finish h2 poll (usually already satisfied) + stage ----
        {
            int guard = 0;
            while (!((PTAG(v2a) == want2) & (PTAG(v2b) == want2))) {
                v2a = ld_pair(h2p); v2b = ld_pair(h2p + 1);
                if (++guard > (1 << 17)) break;  // hang insurance only
            }
        }
        float sb0 = PVAL(v2a), sb1 = PVAL(v2b);
        h2s[sdst] = pk2(sb0, sb1);
        __syncthreads();   // S2b: h2s staged

        // ---- B-dot: accB += W_hh2 . h2 ----
        BSTEP(0); BSTEP(1); BSTEP(2); BSTEP(3);

        float accB = e0 + e1;
        accB += __shfl_xor(accB, 1);
        accB += __shfl_xor(accB, 2);
        accB += __shfl_xor(accB, 4);
        accB += __shfl_xor(accB, 8);
        accB += __shfl_xor(accB, 16);
        if (c == 0) {
            float vB = accB + bsum2;
            g2[gate][rsub] = (gate == 2) ? tanh_f(vB) : sigmoid_f(vB);
        }
        __syncthreads();   // S3: g2 ready; also fences LDS reuse next phase

        if (p >= 1 && tid >= 4 && tid < 8) {
            int u = tid - 4;
            float iv = g2[0][u], fv = g2[1][u];
            float gv = g2[2][u], ov = g2[3][u];
            float cn = fv * c2s[u] + iv * gv;
            c2s[u] = cn;
            const int wr = use_hist ? p : (p & 1);
            st_pair(h2t + (size_t)wr * 1024 + (wg << 2) + u,
                    ov * tanh_f(cn), (u32)(p + 1));
        }

        // ---- fallback out-path (no hist workspace): WG0, out(p-2) ----
        if (!use_hist && wg == 0 && p >= 2) {
            const float2 wo0 = *(const float2*)(Wout + (tid << 1));
            const float2 wo1 = *(const float2*)(Wout + HID + (tid << 1));
            float q0 = wo0.x * sb0 + wo0.y * sb1;
            float q1 = wo1.x * sb0 + wo1.y * sb1;
            #pragma unroll
            for (int m = 1; m < 64; m <<= 1) {
                q0 += __shfl_xor(q0, m);
                q1 += __shfl_xor(q1, m);
            }
            if (lane == 0) { red0[wave] = q0; red1[wave] = q1; }
            __syncthreads();
            if (tid == 0) {
                float o0 = bout[0], o1 = bout[1];
                #pragma unroll
                for (int w = 0; w < 8; ++w) { o0 += red0[w]; o1 += red1[w]; }
                out[2*(p-2)+0] = o0;
                out[2*(p-2)+1] = o1;
            }
            __syncthreads();
        }
        // no grid barrier: next phase's poll is the synchronization
    }

    // ---- epilogue ----
    if (use_hist) {
        const float2 wo0 = *(const float2*)(Wout + (tid << 1));
        const float2 wo1 = *(const float2*)(Wout + HID + (tid << 1));
        const float bo0 = bout[0], bo1 = bout[1];
        for (int i = 0; i < 16; ++i) {
            const int t = (wg << 4) + i;
            const u64* hp = h2t + (size_t)(t + 1) * 1024 + (tid << 1);
            const u32 want = (u32)(t + 2);
            u64 va, vb; int guard = 0;
            for (;;) {
                va = ld_pair(hp); vb = ld_pair(hp + 1);
                if ((PTAG(va) == want) && (PTAG(vb) == want)) break;
                if (++guard > (1 << 15)) break;
            }
            float h0 = PVAL(va), h1v = PVAL(vb);
            float q0 = wo0.x * h0 + wo0.y * h1v;
            float q1 = wo1.x * h0 + wo1.y * h1v;
            #pragma unroll
            for (int m = 1; m < 64; m <<= 1) {
                q0 += __shfl_xor(q0, m);
                q1 += __shfl_xor(q1, m);
            }
            if (lane == 0) { red0[wave] = q0; red1[wave] = q1; }
            __syncthreads();
            if (tid == 0) {
                float o0 = bo0, o1 = bo1;
                #pragma unroll
                for (int w = 0; w < 8; ++w) { o0 += red0[w]; o1 += red1[w]; }
                out[2*t+0] = o0;
                out[2*t+1] = o1;
            }
            __syncthreads();
        }
    } else if (wg == 0) {
        // final out[T-1]: h2(T-1) written phase TSTEPS -> row TSTEPS&1 = 0,
        // tag TSTEPS+1
        const float2 wo0 = *(const float2*)(Wout + (tid << 1));
        const float2 wo1 = *(const float2*)(Wout + HID + (tid << 1));
        const u64* hp = h2t + (size_t)(TSTEPS & 1) * 1024 + (tid << 1);
        const u32 want = (u32)(TSTEPS + 1);
        u64 va, vb; int guard = 0;
        for (;;) {
            va = ld_pair(hp); vb = ld_pair(hp + 1);
            if ((PTAG(va) == want) && (PTAG(vb) == want)) break;
            if (++guard > (1 << 15)) break;
        }
        float h0 = PVAL(va), h1v = PVAL(vb);
        float q0 = wo0.x * h0 + wo0.y * h1v;
        float q1 = wo1.x * h0 + wo1.y * h1v;
        #pragma unroll
        for (int m = 1; m < 64; m <<= 1) {
            q0 += __shfl_xor(q0, m);
            q1 += __shfl_xor(q1, m);
        }
        if (lane == 0) { red0[wave] = q0; red1[wave] = q1; }
        __syncthreads();
        if (tid == 0) {
            float o0 = bout[0], o1 = bout[1];
            #pragma unroll
            for (int w = 0; w < 8; ++w) { o0 += red0[w]; o1 += red1[w]; }
            out[2*(TSTEPS-1)+0] = o0;
            out[2*(TSTEPS-1)+1] = o1;
        }
    }
}

extern "C" void kernel_launch(void* const* d_in, const int* in_sizes, int n_in,
                              void* d_out, int out_size, void* d_ws, size_t ws_size,
                              hipStream_t stream)
{
    const float* x    = (const float*)d_in[0];
    const float* Wih1 = (const float*)d_in[1];
    const float* Whh1 = (const float*)d_in[2];
    const float* bih1 = (const float*)d_in[3];
    const float* bhh1 = (const float*)d_in[4];
    const float* Wih2 = (const float*)d_in[5];
    const float* Whh2 = (const float*)d_in[6];
    const float* bih2 = (const float*)d_in[7];
    const float* bhh2 = (const float*)d_in[8];
    const float* Wout = (const float*)d_in[9];
    const float* bout = (const float*)d_in[10];
    float* out = (float*)d_out;
    u64*   ws  = (u64*)d_ws;

    const int use_hist = (ws_size >= WS_NEED_BYTES) ? 1 : 0;

    // allow >64KB dynamic LDS (idempotent, not stream-ordered: capture-safe)
    (void)hipFuncSetAttribute((const void*)lstm_persistent,
                              hipFuncAttributeMaxDynamicSharedMemorySize,
                              DYN_LDS_BYTES);

    // zero h1 slots + h2 rows 0..1 (ws re-poisoned 0xAA before every call;
    // poison can never equal a wanted tag, so un-zeroed hist rows are safe)
    (void)hipMemsetAsync(d_ws, 0, WS_ZERO_BYTES, stream);

    hipLaunchKernelGGL(lstm_persistent, dim3(NWG), dim3(TPB), DYN_LDS_BYTES,
                       stream,
                       x, Wih1, Whh1, bih1, bhh1,
                       Wih2, Whh2, bih2, bhh2,
                       Wout, bout, out, ws, use_hist);
}

// Round 2
// 7699.928 us; speedup vs baseline: 1.2803x; 1.2803x over previous
//
#include <hip/hip_runtime.h>
#include <math.h>

// LSTM_53171695124900: 2-layer LSTM, H=1024, I=64, O=2, T=4096.
// Persistent kernel, 256 WGs x 512 threads.
// Round-12 = REVERT to the proven r10 phase structure (r11's reorder +
// depth-2 poll regressed 30%: doubled poll issue rate into the IC
// hotspot, extra barrier, no detection-granularity gain), plus ONE
// change: h1 transits the workspace as f16x2 + tag in a single u64.
//   - every h1 consumer already converts to f16 (pk2) before the dots,
//     so producer-side packing is BIT-IDENTICAL math;
//   - h1 poll: 1 load/thread/iter (was 2)  -> hotspot traffic halved;
//   - h1 publish: 2 stores/WG (was 4); tags to straggle on: 512 (was 1024);
//   - consumer stage step loses its v_cvt_pkrtz (payload is already f16x2).
// h2 protocol, gates, barriers, out-paths: exactly r10.

#define HID 1024
#define DIN 64
#define TSTEPS 4096
#define NWG 256
#define TPB 512

typedef unsigned long long u64;
typedef unsigned int u32;
typedef _Float16 f16x2 __attribute__((ext_vector_type(2)));
typedef __fp16   g16x2 __attribute__((ext_vector_type(2)));

// ws layout in u64 (8B tagged entries):
//   [0, 1024)                 : h1 packed entries, 2 slots x 512
//                               (tag<<32 | f16x2 payload = elems 2q,2q+1)
//   [2048, 2048 + 4097*1024)  : h2 pairs (f32 + tag); hist mode = row per
//                               phase, fallback mode = rows (phase & 1)
#define H2_OFF 2048
#define WS_NEED_U64 (2048ull + 4097ull * 1024ull)
#define WS_NEED_BYTES (WS_NEED_U64 * 8ull)
#define WS_ZERO_BYTES 32768   // h1 slots (8KB used) + h2 rows 0..1 (16KB)

// dynamic LDS: 8*512 uint4 f16 weights (64KB) + 2 x 640-u32 h staging
#define WLDS_U4 (8 * 512)
#define H1S_OFF (WLDS_U4 * 16)            // bytes
#define H2S_OFF (H1S_OFF + 640 * 4)
#define DYN_LDS_BYTES (H2S_OFF + 640 * 4) // 70656 B

__device__ __forceinline__ float sigmoid_f(float v) {
    return 1.0f / (1.0f + __expf(-v));
}
__device__ __forceinline__ float tanh_f(float v) {
    return 2.0f / (1.0f + __expf(-2.0f * v)) - 1.0f;
}

// relaxed agent-scope 8B atomics: coherent at IC, no cache-maintenance insts
__device__ __forceinline__ void st_u64(u64* p, u64 v) {
    __hip_atomic_store(p, v, __ATOMIC_RELAXED, __HIP_MEMORY_SCOPE_AGENT);
}
__device__ __forceinline__ void st_pair(u64* p, float h, u32 tag) {
    u64 pk = ((u64)tag << 32) | (u64)__float_as_uint(h);
    __hip_atomic_store(p, pk, __ATOMIC_RELAXED, __HIP_MEMORY_SCOPE_AGENT);
}
__device__ __forceinline__ u64 ld_pair(const u64* p) {
    return __hip_atomic_load(p, __ATOMIC_RELAXED, __HIP_MEMORY_SCOPE_AGENT);
}
#define PTAG(v) ((u32)((v) >> 32))
#define PVAL(v) (__uint_as_float((u32)(v)))

// same 4 bytes seen as u32 / __fp16x2 (cvt_pkrtz) / _Float16x2 (fdot2)
union U32H2 { u32 u; f16x2 h; g16x2 g; };

// pack two f32 -> half2 u32 (v_cvt_pkrtz_f16_f32, single inst)
__device__ __forceinline__ u32 pk2(float a, float b) {
    U32H2 t; t.g = __builtin_amdgcn_cvt_pkrtz(a, b); return t.u;
}

#if defined(__has_builtin)
#if __has_builtin(__builtin_amdgcn_fdot2)
#define HAS_FDOT2 1
#endif
#endif

// f32 += half2 . half2  (v_dot2_f32_f16 when available)
__device__ __forceinline__ float dot2f(u32 a, u32 b, float c) {
    U32H2 x, y; x.u = a; y.u = b;
#ifdef HAS_FDOT2
    return __builtin_amdgcn_fdot2(x.h, y.h, c, false);
#else
    float r = fmaf((float)x.h.x, (float)y.h.x, c);
    return fmaf((float)x.h.y, (float)y.h.y, r);
#endif
}

#define PIN_W1() asm volatile("" : "+v"(w1p0), "+v"(w1p1), "+v"(w1p2), \
    "+v"(w1p3), "+v"(w1p4), "+v"(w1p5), "+v"(w1p6), "+v"(w1p7), \
    "+v"(w1p8), "+v"(w1p9), "+v"(w1pA), "+v"(w1pB), \
    "+v"(w1pC), "+v"(w1pD), "+v"(w1pE), "+v"(w1pF))

// A-step j (j=0..3): 8 h1 elems; W1 (reg half2s) -> accA, W2 (LDS) -> accB
#define ASTEP(j, P0, P1, P2, P3) do {                               \
    uint4 hv = *(const uint4*)(h1s + hbase + 4*(j));                \
    uint4 w2 = wlds[(j)*512 + tid];                                 \
    a0 = dot2f(hv.x, P0, a0); a1 = dot2f(hv.y, P1, a1);             \
    a0 = dot2f(hv.z, P2, a0); a1 = dot2f(hv.w, P3, a1);             \
    e0 = dot2f(hv.x, w2.x, e0); e1 = dot2f(hv.y, w2.y, e1);         \
    e0 = dot2f(hv.z, w2.z, e0); e1 = dot2f(hv.w, w2.w, e1);         \
} while (0)

// B-step j (j=0..3): 8 h2 elems; W3 (LDS) -> accB
#define BSTEP(j) do {                                               \
    uint4 gv = *(const uint4*)(h2s + hbase + 4*(j));                \
    uint4 w3 = wlds[(4+(j))*512 + tid];                             \
    e0 = dot2f(gv.x, w3.x, e0); e1 = dot2f(gv.y, w3.y, e1);         \
    e0 = dot2f(gv.z, w3.z, e0); e1 = dot2f(gv.w, w3.w, e1);         \
} while (0)

__global__ void
__attribute__((amdgpu_flat_work_group_size(TPB, TPB), amdgpu_waves_per_eu(2, 2)))
lstm_persistent(
    const float* __restrict__ x,
    const float* __restrict__ Wih1, const float* __restrict__ Whh1,
    const float* __restrict__ bih1, const float* __restrict__ bhh1,
    const float* __restrict__ Wih2, const float* __restrict__ Whh2,
    const float* __restrict__ bih2, const float* __restrict__ bhh2,
    const float* __restrict__ Wout, const float* __restrict__ bout,
    float* __restrict__ out, u64* __restrict__ ws, int use_hist)
{
    const int wg   = blockIdx.x;          // 0..255
    const int tid  = threadIdx.x;         // 0..511
    const int wave = tid >> 6;            // 0..7
    const int lane = tid & 63;
    const int gate = tid >> 7;            // 0..3 (i,f,g,o)
    const int rsub = (tid >> 5) & 3;      // local unit 0..3
    const int c    = tid & 31;            // k-chunk 0..31
    const int row  = gate * HID + (wg << 2) + rsub;   // gate row in [0,4096)
    const int kbase = c << 5;

    u64* h1t = ws;
    u64* h2t = ws + H2_OFF;

    // ---- dynamic LDS carve ----
    extern __shared__ __align__(16) char smem[];
    uint4* wlds = (uint4*)smem;                  // 64KB f16 weights
    u32*   h1s  = (u32*)(smem + H1S_OFF);        // 640 u32 (stride-20 rows)
    u32*   h2s  = (u32*)(smem + H2S_OFF);        // 640 u32

    // ---- one-time: stage W_ih2/W_hh2 rows into LDS as packed f16 ----
    {
        const float4* q2 = (const float4*)(Wih2 + (size_t)row * HID + kbase);
        const float4* q3 = (const float4*)(Whh2 + (size_t)row * HID + kbase);
        #pragma unroll
        for (int j = 0; j < 4; ++j) {
            float4 qa = q2[2*j], qb = q2[2*j+1];
            wlds[j * 512 + tid] = make_uint4(pk2(qa.x, qa.y), pk2(qa.z, qa.w),
                                             pk2(qb.x, qb.y), pk2(qb.z, qb.w));
        }
        #pragma unroll
        for (int j = 0; j < 4; ++j) {
            float4 qa = q3[2*j], qb = q3[2*j+1];
            wlds[(4+j) * 512 + tid] = make_uint4(pk2(qa.x, qa.y), pk2(qa.z, qa.w),
                                                 pk2(qb.x, qb.y), pk2(qb.z, qb.w));
        }
    }

    // ---- W_hh1 row chunk: 16 packed-half2 u32 registers ----
    const float4* p1 = (const float4*)(Whh1 + (size_t)row * HID + kbase);
    float4 f0 = p1[0], f1 = p1[1], f2 = p1[2], f3 = p1[3];
    float4 f4 = p1[4], f5 = p1[5], f6 = p1[6], f7 = p1[7];
    u32 w1p0 = pk2(f0.x, f0.y), w1p1 = pk2(f0.z, f0.w);
    u32 w1p2 = pk2(f1.x, f1.y), w1p3 = pk2(f1.z, f1.w);
    u32 w1p4 = pk2(f2.x, f2.y), w1p5 = pk2(f2.z, f2.w);
    u32 w1p6 = pk2(f3.x, f3.y), w1p7 = pk2(f3.z, f3.w);
    u32 w1p8 = pk2(f4.x, f4.y), w1p9 = pk2(f4.z, f4.w);
    u32 w1pA = pk2(f5.x, f5.y), w1pB = pk2(f5.z, f5.w);
    u32 w1pC = pk2(f6.x, f6.y), w1pD = pk2(f6.z, f6.w);
    u32 w1pE = pk2(f7.x, f7.y), w1pF = pk2(f7.z, f7.w);
    PIN_W1();

    const float2 wx = *(const float2*)(Wih1 + (size_t)row * DIN + (c << 1));
    const float bsum1 = bih1[row] + bhh1[row];
    const float bsum2 = bih2[row] + bhh2[row];

    __shared__ float g1[4][4], g2[4][4];
    __shared__ float c1s[4], c2s[4];
    __shared__ float red0[8], red1[8];
    if (tid < 4) { c1s[tid] = 0.0f; c2s[tid] = 0.0f; }

    // h staging: chunk rows of 16 half2-u32 + 4 pad (stride 20 u32, 80B)
    const int sdst = 20 * (tid >> 4) + (tid & 15);
    const int hbase = 20 * c;

    __syncthreads();   // wlds staged, c-state zeroed

    for (int p = 0; p <= TSTEPS; ++p) {
        // h1: ONE packed entry per thread (elems 2*tid, 2*tid+1 as f16x2)
        const u64* h1p = h1t + (size_t)(p & 1) * 512 + tid;
        const int h2row_c = (p > 0) ? (use_hist ? (p - 1) : ((p - 1) & 1)) : 0;
        const u64* h2p = h2t + (size_t)h2row_c * 1024 + (tid << 1);
        const u32 want1 = (u32)p;
        const u32 want2 = (p >= 2) ? (u32)p : 0u;

        const int tx = (p < TSTEPS) ? p : 0;
        const float2 xv = *(const float2*)(x + (size_t)tx * DIN + (c << 1));

        // ---- blocking poll: h1(p-1), tag p (published mid-phase p-1) ----
        u64 v1;
        {
            int guard = 0;
            for (;;) {
                v1 = ld_pair(h1p);
                if (PTAG(v1) == want1) break;
                if (++guard > (1 << 17)) break;  // hang insurance only
            }
        }
        // early h2 read attempt (verified after the A-dot)
        u64 v2a = ld_pair(h2p), v2b = ld_pair(h2p + 1);

        PIN_W1();   // keepalive: W1 VGPR-resident every phase

        h1s[sdst] = (u32)v1;   // payload is already f16x2
        __syncthreads();   // S1: h1s staged

        // ---- A-dot: accA = W_hh1.h1 (+x); accB partial = W_ih2.h1 ----
        float a0 = 0.f, a1 = 0.f, e0 = 0.f, e1 = 0.f;
        ASTEP(0, w1p0, w1p1, w1p2, w1p3);
        ASTEP(1, w1p4, w1p5, w1p6, w1p7);
        ASTEP(2, w1p8, w1p9, w1pA, w1pB);
        ASTEP(3, w1pC, w1pD, w1pE, w1pF);
        a0 = fmaf(wx.x, xv.x, a0);
        a1 = fmaf(wx.y, xv.y, a1);

        float accA = a0 + a1;
        accA += __shfl_xor(accA, 1);
        accA += __shfl_xor(accA, 2);
        accA += __shfl_xor(accA, 4);
        accA += __shfl_xor(accA, 8);
        accA += __shfl_xor(accA, 16);
        if (c == 0) {
            float vA = accA + bsum1;
            g1[gate][rsub] = (gate == 2) ? tanh_f(vA) : sigmoid_f(vA);
        }

        // ---- finish h2 poll (usually already satisfied) + stage ----
        {
            int guard = 0;
            while (!((PTAG(v2a) == want2) & (PTAG(v2b) == want2))) {
                v2a = ld_pair(h2p); v2b = ld_pair(h2p + 1);
                if (++guard > (1 << 17)) break;  // hang insurance only
            }
        }
        float sb0 = PVAL(v2a), sb1 = PVAL(v2b);
        h2s[sdst] = pk2(sb0, sb1);
        __syncthreads();   // S2: g1 + h2s ready

        // ---- EARLY h1 publication: before the heavy B-part ----
        // tid 0/1 each handle 2 units, packed into one tagged u64
        if (p < TSTEPS && tid < 2) {
            const int u0 = tid << 1, u1 = u0 + 1;
            float iv0 = g1[0][u0], fv0 = g1[1][u0];
            float gv0 = g1[2][u0], ov0 = g1[3][u0];
            float iv1 = g1[0][u1], fv1 = g1[1][u1];
            float gv1 = g1[2][u1], ov1 = g1[3][u1];
            float cn0 = fv0 * c1s[u0] + iv0 * gv0;  c1s[u0] = cn0;
            float cn1 = fv1 * c1s[u1] + iv1 * gv1;  c1s[u1] = cn1;
            float h0 = ov0 * tanh_f(cn0);
            float h1v = ov1 * tanh_f(cn1);
            u64 pkv = ((u64)(u32)(p + 1) << 32) | (u64)pk2(h0, h1v);
            st_u64(h1t + (size_t)((p + 1) & 1) * 512 + (wg << 1) + tid, pkv);
        }

        // ---- B-dot: accB += W_hh2.h2 ----
        BSTEP(0); BSTEP(1); BSTEP(2); BSTEP(3);

        float accB = e0 + e1;
        accB += __shfl_xor(accB, 1);
        accB += __shfl_xor(accB, 2);
        accB += __shfl_xor(accB, 4);
        accB += __shfl_xor(accB, 8);
        accB += __shfl_xor(accB, 16);
        if (c == 0) {
            float vB = accB + bsum2;
            g2[gate][rsub] = (gate == 2) ? tanh_f(vB) : sigmoid_f(vB);
        }
        __syncthreads();   // S3: g2 ready; also fences LDS reuse next phase

        if (p >= 1 && tid >= 4 && tid < 8) {
            int u = tid - 4;
            float iv = g2[0][u], fv = g2[1][u];
            float gv = g2[2][u], ov = g2[3][u];
            float cn = fv * c2s[u] + iv * gv;
            c2s[u] = cn;
            const int wr = use_hist ? p : (p & 1);
            st_pair(h2t + (size_t)wr * 1024 + (wg << 2) + u,
                    ov * tanh_f(cn), (u32)(p + 1));
        }

        // ---- fallback out-path (no hist workspace): WG0, out(p-2) ----
        if (!use_hist && wg == 0 && p >= 2) {
            const float2 wo0 = *(const float2*)(Wout + (tid << 1));
            const float2 wo1 = *(const float2*)(Wout + HID + (tid << 1));
            float q0 = wo0.x * sb0 + wo0.y * sb1;
            float q1 = wo1.x * sb0 + wo1.y * sb1;
            #pragma unroll
            for (int m = 1; m < 64; m <<= 1) {
                q0 += __shfl_xor(q0, m);
                q1 += __shfl_xor(q1, m);
            }
            if (lane == 0) { red0[wave] = q0; red1[wave] = q1; }
            __syncthreads();
            if (tid == 0) {
                float o0 = bout[0], o1 = bout[1];
                #pragma unroll
                for (int w = 0; w < 8; ++w) { o0 += red0[w]; o1 += red1[w]; }
                out[2*(p-2)+0] = o0;
                out[2*(p-2)+1] = o1;
            }
            __syncthreads();
        }
        // no grid barrier: next phase's poll is the synchronization
    }

    // ---- epilogue ----
    if (use_hist) {
        const float2 wo0 = *(const float2*)(Wout + (tid << 1));
        const float2 wo1 = *(const float2*)(Wout + HID + (tid << 1));
        const float bo0 = bout[0], bo1 = bout[1];
        for (int i = 0; i < 16; ++i) {
            const int t = (wg << 4) + i;
            const u64* hp = h2t + (size_t)(t + 1) * 1024 + (tid << 1);
            const u32 want = (u32)(t + 2);
            u64 va, vb; int guard = 0;
            for (;;) {
                va = ld_pair(hp); vb = ld_pair(hp + 1);
                if ((PTAG(va) == want) && (PTAG(vb) == want)) break;
                if (++guard > (1 << 15)) break;
            }
            float h0 = PVAL(va), h1v = PVAL(vb);
            float q0 = wo0.x * h0 + wo0.y * h1v;
            float q1 = wo1.x * h0 + wo1.y * h1v;
            #pragma unroll
            for (int m = 1; m < 64; m <<= 1) {
                q0 += __shfl_xor(q0, m);
                q1 += __shfl_xor(q1, m);
            }
            if (lane == 0) { red0[wave] = q0; red1[wave] = q1; }
            __syncthreads();
            if (tid == 0) {
                float o0 = bo0, o1 = bo1;
                #pragma unroll
                for (int w = 0; w < 8; ++w) { o0 += red0[w]; o1 += red1[w]; }
                out[2*t+0] = o0;
                out[2*t+1] = o1;
            }
            __syncthreads();
        }
    } else if (wg == 0) {
        // final out[T-1]: h2(T-1) written phase TSTEPS -> row TSTEPS&1 = 0,
        // tag TSTEPS+1
        const float2 wo0 = *(const float2*)(Wout + (tid << 1));
        const float2 wo1 = *(const float2*)(Wout + HID + (tid << 1));
        const u64* hp = h2t + (size_t)(TSTEPS & 1) * 1024 + (tid << 1);
        const u32 want = (u32)(TSTEPS + 1);
        u64 va, vb; int guard = 0;
        for (;;) {
            va = ld_pair(hp); vb = ld_pair(hp + 1);
            if ((PTAG(va) == want) && (PTAG(vb) == want)) break;
            if (++guard > (1 << 15)) break;
        }
        float h0 = PVAL(va), h1v = PVAL(vb);
        float q0 = wo0.x * h0 + wo0.y * h1v;
        float q1 = wo1.x * h0 + wo1.y * h1v;
        #pragma unroll
        for (int m = 1; m < 64; m <<= 1) {
            q0 += __shfl_xor(q0, m);
            q1 += __shfl_xor(q1, m);
        }
        if (lane == 0) { red0[wave] = q0; red1[wave] = q1; }
        __syncthreads();
        if (tid == 0) {
            float o0 = bout[0], o1 = bout[1];
            #pragma unroll
            for (int w = 0; w < 8; ++w) { o0 += red0[w]; o1 += red1[w]; }
            out[2*(TSTEPS-1)+0] = o0;
            out[2*(TSTEPS-1)+1] = o1;
        }
    }
}

extern "C" void kernel_launch(void* const* d_in, const int* in_sizes, int n_in,
                              void* d_out, int out_size, void* d_ws, size_t ws_size,
                              hipStream_t stream)
{
    const float* x    = (const float*)d_in[0];
    const float* Wih1 = (const float*)d_in[1];
    const float* Whh1 = (const float*)d_in[2];
    const float* bih1 = (const float*)d_in[3];
    const float* bhh1 = (const float*)d_in[4];
    const float* Wih2 = (const float*)d_in[5];
    const float* Whh2 = (const float*)d_in[6];
    const float* bih2 = (const float*)d_in[7];
    const float* bhh2 = (const float*)d_in[8];
    const float* Wout = (const float*)d_in[9];
    const float* bout = (const float*)d_in[10];
    float* out = (float*)d_out;
    u64*   ws  = (u64*)d_ws;

    const int use_hist = (ws_size >= WS_NEED_BYTES) ? 1 : 0;

    // allow >64KB dynamic LDS (idempotent, not stream-ordered: capture-safe)
    (void)hipFuncSetAttribute((const void*)lstm_persistent,
                              hipFuncAttributeMaxDynamicSharedMemorySize,
                              DYN_LDS_BYTES);

    // zero h1 slots + h2 rows 0..1 (ws re-poisoned 0xAA before every call;
    // poison can never equal a wanted tag, so un-zeroed hist rows are safe)
    (void)hipMemsetAsync(d_ws, 0, WS_ZERO_BYTES, stream);

    hipLaunchKernelGGL(lstm_persistent, dim3(NWG), dim3(TPB), DYN_LDS_BYTES,
                       stream,
                       x, Wih1, Whh1, bih1, bhh1,
                       Wih2, Whh2, bih2, bhh2,
                       Wout, bout, out, ws, use_hist);
}